// Round 12
// baseline (375.093 us; speedup 1.0000x reference)
//
#include <hip/hip_runtime.h>

// GraphSAGE (pool aggregator, 2 layers) on MI355X.
// Round 12: minimize total fabric bytes (everything is traffic-bound now).
//   - sn_pool gains pass 4: out = H(LDS h1 tile) @ sw2^T + b_sn2 -> the h1
//     global round-trip (25.6 MB write + 25.6 MB read) is deleted entirely.
//   - final GEMM slims to out_acc: out += agg @ nw2^T (acc init from out).
//   Net traffic -19 MB; final-pair-0 work rides inside sn_pool.
// Gathers (fabric floor), CSR build, scatter_pool unchanged from round 11.

#define N_FEAT 128
#define NWG_A 256
#define BSHIFT 10            // 1024 nodes per bucket
#define NBMAX 128

typedef __attribute__((ext_vector_type(8))) short bf16x8;            // 8 bf16 = 4 VGPRs
typedef __attribute__((ext_vector_type(8))) unsigned short u16x8;    // 16 B
typedef __attribute__((ext_vector_type(4))) float f32x4;

static __device__ __forceinline__ unsigned short f2bf(float f) {
    unsigned u = __float_as_uint(f);
    unsigned r = (u + 0x7fffu + ((u >> 16) & 1u)) >> 16;   // RNE
    return (unsigned short)r;
}

static __device__ __forceinline__ bf16x8 loadA_f32(const float* __restrict__ A, size_t idx) {
    float4 a = *(const float4*)&A[idx];
    float4 b = *(const float4*)&A[idx + 4];
    bf16x8 r;
    r[0] = (short)f2bf(a.x); r[1] = (short)f2bf(a.y);
    r[2] = (short)f2bf(a.z); r[3] = (short)f2bf(a.w);
    r[4] = (short)f2bf(b.x); r[5] = (short)f2bf(b.y);
    r[6] = (short)f2bf(b.z); r[7] = (short)f2bf(b.w);
    return r;
}

// ---------------- prep (weights->bf16, fused biases) + bin_count merged ----------------
__global__ __launch_bounds__(256) void prep_bin_kernel(
    const float* __restrict__ pw1, const float* __restrict__ sw1,
    const float* __restrict__ nw1, const float* __restrict__ pw2,
    const float* __restrict__ sw2, const float* __restrict__ nw2,
    const float* __restrict__ sb1, const float* __restrict__ nb1,
    const float* __restrict__ sb2, const float* __restrict__ nb2,
    unsigned short* __restrict__ wb_p1, unsigned short* __restrict__ wb_s1,
    unsigned short* __restrict__ wb_n1, unsigned short* __restrict__ wb_p2,
    unsigned short* __restrict__ wb_s2, unsigned short* __restrict__ wb_n2,
    float* __restrict__ b_sn1, float* __restrict__ b_sn2,
    const int* __restrict__ dst, int* __restrict__ wgcnt, int E, int NB)
{
    __shared__ int cnt[NBMAX];
    if (blockIdx.x < NWG_A) {
        const int wg = blockIdx.x, tid = threadIdx.x;
        if (tid < NB) cnt[tid] = 0;
        __syncthreads();
        const int slab = (E + NWG_A - 1) / NWG_A;
        const int e0 = wg * slab;
        const int e1 = min(e0 + slab, E);
        for (int e = e0 + tid; e < e1; e += 256)
            atomicAdd(&cnt[dst[e] >> BSHIFT], 1);
        __syncthreads();
        if (tid < NB) wgcnt[tid * NWG_A + wg] = cnt[tid];
    } else {
        int t = (blockIdx.x - NWG_A) * 256 + threadIdx.x;
        if (t < 16384) {
            wb_p1[t] = f2bf(pw1[t]);
            wb_s1[t] = f2bf(sw1[t]);
            wb_n1[t] = f2bf(nw1[t]);
            wb_p2[t] = f2bf(pw2[t]);
        }
        if (t < 6144) {                   // 48x128, rows 40..47 zero-padded
            int row = t >> 7;
            wb_s2[t] = (row < 40) ? f2bf(sw2[t]) : 0;
            wb_n2[t] = (row < 40) ? f2bf(nw2[t]) : 0;
        }
        if (t < 128) b_sn1[t] = sb1[t] + nb1[t];
        if (t < 64)  b_sn2[t] = (t < 40) ? (sb2[t] + nb2[t]) : 0.f;
    }
}

// ---------------- bin_scan: 1024-thread exclusive scan of NB*NWG_A counts ----------------
__global__ __launch_bounds__(1024) void bin_scan_kernel(const int* __restrict__ wgcnt,
                                                        int* __restrict__ binoff, int NB)
{
    __shared__ int sh[1024];
    const int t = threadIdx.x;
    const int total = NB * NWG_A;
    const int chunk = (total + 1023) / 1024;
    const int b0 = t * chunk;
    const int b1 = min(b0 + chunk, total);
    int s = 0;
    for (int k = b0; k < b1; k++) s += wgcnt[k];
    sh[t] = s;
    __syncthreads();
    for (int off = 1; off < 1024; off <<= 1) {
        int x = (t >= off) ? sh[t - off] : 0;
        __syncthreads();
        sh[t] += x;
        __syncthreads();
    }
    int run = sh[t] - s;
    for (int k = b0; k < b1; k++) {
        int v = wgcnt[k];
        binoff[k] = run;
        run += v;
    }
    if (t == 1023) binoff[total] = sh[1023];   // == E
}

// ---------------- scatter_pool: bin_scatter (blocks 0..255) + pool1 GEMM ----------------
__global__ __launch_bounds__(256, 4) void scatter_pool_kernel(
    const int* __restrict__ src, const int* __restrict__ dst,
    const int* __restrict__ binoff, unsigned* __restrict__ binned, int E, int NB,
    const float* __restrict__ A0f, const unsigned short* __restrict__ B0,
    const float* __restrict__ bias, unsigned short* __restrict__ Cout, int M)
{
    __shared__ int cur[NBMAX];
    __shared__ unsigned short Bs[128 * 136];
    __shared__ float BsF[128];

    if (blockIdx.x < NWG_A) {
        // ---- bin_scatter body (plain stores: L2 write-combines wg-private streams) ----
        const int wg = blockIdx.x, tid = threadIdx.x;
        if (tid < NB) cur[tid] = binoff[tid * NWG_A + wg];
        __syncthreads();
        const int slab = (E + NWG_A - 1) / NWG_A;
        const int e0 = wg * slab;
        const int e1 = min(e0 + slab, E);
        for (int e = e0 + tid; e < e1; e += 256) {
            int d = dst[e];
            int b = d >> BSHIFT;
            unsigned rec = ((unsigned)(d & ((1 << BSHIFT) - 1)) << 17) | (unsigned)src[e];
            int p = atomicAdd(&cur[b], 1);
            binned[p] = rec;
        }
        return;
    }

    // ---- pool1 GEMM body ----
    const int tid = threadIdx.x;
    const int w = tid >> 6, lane = tid & 63;
    const int q = lane >> 4, r16 = lane & 15;
    const int m0 = (blockIdx.x - NWG_A) * 128;

    if (tid < 128) BsF[tid] = bias[tid];

    int rowA[2];
#pragma unroll
    for (int rt = 0; rt < 2; rt++) {
        int r = m0 + w * 32 + rt * 16 + r16;
        rowA[rt] = r < M ? r : (M - 1);
    }

    f32x4 acc[2][8];
#pragma unroll
    for (int i = 0; i < 2; i++)
#pragma unroll
        for (int j = 0; j < 8; j++) acc[i][j] = (f32x4){0.f, 0.f, 0.f, 0.f};

    for (int j = tid; j < 2048; j += 256) {
        int row = j >> 4, cc = j & 15;
        *(uint4*)&Bs[row * 136 + cc * 8] = *(const uint4*)&B0[(size_t)row * 128 + cc * 8];
    }
    __syncthreads();

#pragma unroll
    for (int k0 = 0; k0 < 128; k0 += 32) {
        bf16x8 af[2];
#pragma unroll
        for (int rt = 0; rt < 2; rt++)
            af[rt] = loadA_f32(A0f, (size_t)rowA[rt] * 128 + k0 + q * 8);
#pragma unroll
        for (int ct = 0; ct < 8; ct++) {
            bf16x8 bfr = *(const bf16x8*)&Bs[(ct * 16 + r16) * 136 + k0 + q * 8];
#pragma unroll
            for (int rt = 0; rt < 2; rt++)
                acc[rt][ct] = __builtin_amdgcn_mfma_f32_16x16x32_bf16(
                    af[rt], bfr, acc[rt][ct], 0, 0, 0);
        }
    }

#pragma unroll
    for (int rt = 0; rt < 2; rt++) {
#pragma unroll
        for (int ct = 0; ct < 8; ct++) {
            int col = ct * 16 + r16;
#pragma unroll
            for (int r = 0; r < 4; r++) {
                int grow = m0 + w * 32 + rt * 16 + q * 4 + r;
                if (grow < M) {
                    float v = fmaxf(acc[rt][ct][r] + BsF[col], 0.f);
                    Cout[(size_t)grow * 128 + col] = f2bf(v);
                }
            }
        }
    }
}

// ---------------- csr_build: 1024 threads, thread t owns node t of the bucket ----------------
__global__ __launch_bounds__(1024) void csr_build_kernel(const unsigned* __restrict__ binned,
                                                         const int* __restrict__ binoff,
                                                         int* __restrict__ csr,
                                                         int* __restrict__ offsets,
                                                         int* __restrict__ counts, int M)
{
    __shared__ int cnt[1 << BSHIFT];
    __shared__ int pref[1 << BSHIFT];
    const int b = blockIdx.x, t = threadIdx.x;
    const int rs = binoff[b * NWG_A];
    const int re = binoff[(b + 1) * NWG_A];

    cnt[t] = 0;
    __syncthreads();
    for (int i = rs + t; i < re; i += 1024)
        atomicAdd(&cnt[binned[i] >> 17], 1);
    __syncthreads();

    int v = cnt[t];
    pref[t] = v;
    __syncthreads();
    for (int off = 1; off < 1024; off <<= 1) {
        int x = (t >= off) ? pref[t - off] : 0;
        __syncthreads();
        pref[t] += x;
        __syncthreads();
    }
    int excl = pref[t] - v;

    int node = (b << BSHIFT) + t;
    if (node < M) {
        counts[node] = v;
        offsets[node] = rs + excl;
    }
    cnt[t] = excl;                       // reuse as cursor
    __syncthreads();

    for (int i = rs + t; i < re; i += 1024) {
        unsigned r = binned[i];
        int p = atomicAdd(&cnt[r >> 17], 1);
        csr[rs + p] = (int)(r & 0x1FFFFu);
    }
}

// ---------------- pull gather-max (unchanged) ----------------
__global__ __launch_bounds__(256) void gather_max_kernel(
    const u16x8* __restrict__ m16, const int* __restrict__ csr,
    const int* __restrict__ offsets, const int* __restrict__ counts,
    u16x8* __restrict__ agg16, int Nn)
{
    int wid = (blockIdx.x * 256 + threadIdx.x) >> 6;
    int lane = threadIdx.x & 63;
    if (wid >= Nn) return;
    const int g = lane >> 4, c = lane & 15;
    int start = offsets[wid];
    int deg = counts[wid];
    u16x8 acc = (u16x8){0, 0, 0, 0, 0, 0, 0, 0};
    for (int j0 = 0; j0 < deg; j0 += 64) {
        int nb = deg - j0;
        if (nb > 64) nb = 64;
        int sl = csr[start + j0 + (lane < nb ? lane : nb - 1)];
        for (int j = 0; j < nb; j += 4) {
            int jj = j + g;
            if (jj >= nb) jj = nb - 1;
            int s = __shfl(sl, jj);
            u16x8 v = m16[(size_t)s * 16 + c];
            acc = __builtin_elementwise_max(acc, v);
        }
    }
#pragma unroll
    for (int d = 16; d <= 32; d <<= 1) {
        int4 a = *(int4*)&acc;
        int4 t;
        t.x = __shfl_xor(a.x, d);
        t.y = __shfl_xor(a.y, d);
        t.z = __shfl_xor(a.z, d);
        t.w = __shfl_xor(a.w, d);
        acc = __builtin_elementwise_max(acc, *(u16x8*)&t);
    }
    if (g == 0) __builtin_nontemporal_store(acc, &agg16[(size_t)wid * 16 + c]);
}

// ---------------- out_acc: out += agg @ nw2^T (acc initialized from out) ----------------
__global__ __launch_bounds__(256, 4) void out_acc_kernel(
    const unsigned short* __restrict__ agg, const unsigned short* __restrict__ Bn,
    float* __restrict__ out, int M)
{
    constexpr int NT = 3;
    constexpr int NR = NT * 16;                // 48 (rows 40..47 of Bn are zero)
    __shared__ unsigned short Bs[NR * 136];

    const int tid = threadIdx.x;
    const int w = tid >> 6, lane = tid & 63;
    const int q = lane >> 4, r16 = lane & 15;
    const int m0 = blockIdx.x * 128;

    int rowA[2];
#pragma unroll
    for (int rt = 0; rt < 2; rt++) {
        int r = m0 + w * 32 + rt * 16 + r16;
        rowA[rt] = r < M ? r : (M - 1);
    }

    for (int j = tid; j < NR * 16; j += 256) {
        int row = j >> 4, cc = j & 15;
        *(uint4*)&Bs[row * 136 + cc * 8] = *(const uint4*)&Bn[(size_t)row * 128 + cc * 8];
    }

    // init acc from out (C = previous partial: h1@sw2^T + b_sn2)
    f32x4 acc[2][NT];
#pragma unroll
    for (int rt = 0; rt < 2; rt++) {
#pragma unroll
        for (int ct = 0; ct < NT; ct++) {
            int col = ct * 16 + r16;
#pragma unroll
            for (int r = 0; r < 4; r++) {
                int grow = m0 + w * 32 + rt * 16 + q * 4 + r;
                acc[rt][ct][r] = (grow < M && col < 40) ? out[(size_t)grow * 40 + col] : 0.f;
            }
        }
    }
    __syncthreads();

#pragma unroll
    for (int k0 = 0; k0 < 128; k0 += 32) {
        bf16x8 af[2];
#pragma unroll
        for (int rt = 0; rt < 2; rt++)
            af[rt] = *(const bf16x8*)&agg[(size_t)rowA[rt] * 128 + k0 + q * 8];
#pragma unroll
        for (int ct = 0; ct < NT; ct++) {
            bf16x8 bfr = *(const bf16x8*)&Bs[(ct * 16 + r16) * 136 + k0 + q * 8];
#pragma unroll
            for (int rt = 0; rt < 2; rt++)
                acc[rt][ct] = __builtin_amdgcn_mfma_f32_16x16x32_bf16(
                    af[rt], bfr, acc[rt][ct], 0, 0, 0);
        }
    }

#pragma unroll
    for (int rt = 0; rt < 2; rt++) {
#pragma unroll
        for (int ct = 0; ct < NT; ct++) {
            int col = ct * 16 + r16;
#pragma unroll
            for (int r = 0; r < 4; r++) {
                int grow = m0 + w * 32 + rt * 16 + q * 4 + r;
                if (grow < M && col < 40)
                    out[(size_t)grow * 40 + col] = acc[rt][ct][r];
            }
        }
    }
}

// ---------------- sn_pool: 4 passes, h1 never leaves the CU ----------------
// pass 1+2: acc = in@sw1^T + agg@nw1^T ; h1 = relu(acc+b_sn1) -> LDS H only
// pass 3:   m2  = relu(H@pw2^T + pb2)  -> global (gathered next)
// pass 4:   out = H@sw2^T + b_sn2      -> global f32 (out_acc adds agg-term)
// LDS: Bs 128x72 (conflict-free half-K) + H 128x136 + BsF = 53.76 KB, 3 blk/CU.
__global__ __launch_bounds__(256, 3) void sn_pool_kernel(
    const float* __restrict__ A0f, const unsigned short* __restrict__ B0,
    const unsigned short* __restrict__ A1, const unsigned short* __restrict__ B1,
    const float* __restrict__ bias_sn, const unsigned short* __restrict__ Bp,
    const float* __restrict__ bias_p, const unsigned short* __restrict__ Bs2,
    const float* __restrict__ bias_sn2, unsigned short* __restrict__ m2out,
    float* __restrict__ outp, int M)
{
    __shared__ unsigned short Bs[128 * 72];    // stride 72 shorts (36 dw ≡ 4 mod 32)
    __shared__ unsigned short H[128 * 136];    // stride 136 shorts (68 dw ≡ 4 mod 32)
    __shared__ float BsF[128];

    const int tid = threadIdx.x;
    const int w = tid >> 6, lane = tid & 63;
    const int q = lane >> 4, r16 = lane & 15;
    const int m0 = blockIdx.x * 128;

    if (tid < 128) BsF[tid] = bias_sn[tid];

    int rowA[2];
#pragma unroll
    for (int rt = 0; rt < 2; rt++) {
        int r = m0 + w * 32 + rt * 16 + r16;
        rowA[rt] = r < M ? r : (M - 1);
    }

    f32x4 acc[2][8];
#pragma unroll
    for (int i = 0; i < 2; i++)
#pragma unroll
        for (int j = 0; j < 8; j++) acc[i][j] = (f32x4){0.f, 0.f, 0.f, 0.f};

    // ---- passes 1+2: self (A0 f32) then neigh (A1 bf16), accumulate ----
    for (int p = 0; p < 2; p++) {
        const unsigned short* __restrict__ B = p ? B1 : B0;
        for (int kh = 0; kh < 2; kh++) {
            __syncthreads();               // previous Bs stage consumed
            for (int j = tid; j < 1024; j += 256) {
                int row = j >> 3, cc = j & 7;
                *(uint4*)&Bs[row * 72 + cc * 8] =
                    *(const uint4*)&B[(size_t)row * 128 + kh * 64 + cc * 8];
            }
            __syncthreads();
#pragma unroll
            for (int k0i = 0; k0i < 2; k0i++) {
                const int k0 = kh * 64 + k0i * 32;
                const int koff = k0i * 32;
                bf16x8 af[2];
#pragma unroll
                for (int rt = 0; rt < 2; rt++) {
                    if (p == 0)
                        af[rt] = loadA_f32(A0f, (size_t)rowA[rt] * 128 + k0 + q * 8);
                    else
                        af[rt] = *(const bf16x8*)&A1[(size_t)rowA[rt] * 128 + k0 + q * 8];
                }
#pragma unroll
                for (int ct = 0; ct < 8; ct++) {
                    bf16x8 bfr = *(const bf16x8*)&Bs[(ct * 16 + r16) * 72 + koff + q * 8];
#pragma unroll
                    for (int rt = 0; rt < 2; rt++)
                        acc[rt][ct] = __builtin_amdgcn_mfma_f32_16x16x32_bf16(
                            af[rt], bfr, acc[rt][ct], 0, 0, 0);
                }
            }
        }
    }

    // epilogue 1: h1 = relu(acc + b_sn) -> LDS H only (no global write)
#pragma unroll
    for (int rt = 0; rt < 2; rt++) {
#pragma unroll
        for (int ct = 0; ct < 8; ct++) {
            int col = ct * 16 + r16;
#pragma unroll
            for (int r = 0; r < 4; r++) {
                int lr = w * 32 + rt * 16 + q * 4 + r;
                float v = fmaxf(acc[rt][ct][r] + BsF[col], 0.f);
                H[lr * 136 + col] = f2bf(v);
            }
        }
    }
    __syncthreads();                       // H complete; BsF(bias_sn) reads done
    if (tid < 128) BsF[tid] = bias_p[tid];

#pragma unroll
    for (int i = 0; i < 2; i++)
#pragma unroll
        for (int j = 0; j < 8; j++) acc[i][j] = (f32x4){0.f, 0.f, 0.f, 0.f};

    // ---- pass 3: m2 = relu(H @ pw2^T + b_p) ----
    for (int kh = 0; kh < 2; kh++) {
        __syncthreads();                   // Bs stage consumed (also publishes BsF)
        for (int j = tid; j < 1024; j += 256) {
            int row = j >> 3, cc = j & 7;
            *(uint4*)&Bs[row * 72 + cc * 8] =
                *(const uint4*)&Bp[(size_t)row * 128 + kh * 64 + cc * 8];
        }
        __syncthreads();
#pragma unroll
        for (int k0i = 0; k0i < 2; k0i++) {
            const int k0 = kh * 64 + k0i * 32;
            const int koff = k0i * 32;
            bf16x8 af[2];
#pragma unroll
            for (int rt = 0; rt < 2; rt++)
                af[rt] = *(const bf16x8*)&H[(w * 32 + rt * 16 + r16) * 136 + k0 + q * 8];
#pragma unroll
            for (int ct = 0; ct < 8; ct++) {
                bf16x8 bfr = *(const bf16x8*)&Bs[(ct * 16 + r16) * 72 + koff + q * 8];
#pragma unroll
                for (int rt = 0; rt < 2; rt++)
                    acc[rt][ct] = __builtin_amdgcn_mfma_f32_16x16x32_bf16(
                        af[rt], bfr, acc[rt][ct], 0, 0, 0);
            }
        }
    }

#pragma unroll
    for (int rt = 0; rt < 2; rt++) {
#pragma unroll
        for (int ct = 0; ct < 8; ct++) {
            int col = ct * 16 + r16;
#pragma unroll
            for (int r = 0; r < 4; r++) {
                int grow = m0 + w * 32 + rt * 16 + q * 4 + r;
                if (grow < M) {
                    float v = fmaxf(acc[rt][ct][r] + BsF[col], 0.f);
                    m2out[(size_t)grow * 128 + col] = f2bf(v);
                }
            }
        }
    }

    // ---- pass 4: out = H @ sw2^T + b_sn2 (final pair-0; out_acc adds agg-term) ----
    f32x4 acc2[2][3];
#pragma unroll
    for (int i = 0; i < 2; i++)
#pragma unroll
        for (int j = 0; j < 3; j++) acc2[i][j] = (f32x4){0.f, 0.f, 0.f, 0.f};

    for (int kh = 0; kh < 2; kh++) {
        __syncthreads();                   // pass-3 Bs/BsF reads done
        for (int j = tid; j < 384; j += 256) {      // 48 rows x 8 chunks
            int row = j >> 3, cc = j & 7;
            *(uint4*)&Bs[row * 72 + cc * 8] =
                *(const uint4*)&Bs2[(size_t)row * 128 + kh * 64 + cc * 8];
        }
        if (kh == 0 && tid < 64) BsF[tid] = bias_sn2[tid];
        __syncthreads();
#pragma unroll
        for (int k0i = 0; k0i < 2; k0i++) {
            const int k0 = kh * 64 + k0i * 32;
            const int koff = k0i * 32;
            bf16x8 af[2];
#pragma unroll
            for (int rt = 0; rt < 2; rt++)
                af[rt] = *(const bf16x8*)&H[(w * 32 + rt * 16 + r16) * 136 + k0 + q * 8];
#pragma unroll
            for (int ct = 0; ct < 3; ct++) {
                bf16x8 bfr = *(const bf16x8*)&Bs[(ct * 16 + r16) * 72 + koff + q * 8];
#pragma unroll
                for (int rt = 0; rt < 2; rt++)
                    acc2[rt][ct] = __builtin_amdgcn_mfma_f32_16x16x32_bf16(
                        af[rt], bfr, acc2[rt][ct], 0, 0, 0);
            }
        }
    }

#pragma unroll
    for (int rt = 0; rt < 2; rt++) {
#pragma unroll
        for (int ct = 0; ct < 3; ct++) {
            int col = ct * 16 + r16;
#pragma unroll
            for (int r = 0; r < 4; r++) {
                int grow = m0 + w * 32 + rt * 16 + q * 4 + r;
                if (grow < M && col < 40)
                    outp[(size_t)grow * 40 + col] = acc2[rt][ct][r] + BsF[col];
            }
        }
    }
}

extern "C" void kernel_launch(void* const* d_in, const int* in_sizes, int n_in,
                              void* d_out, int out_size, void* d_ws, size_t ws_size,
                              hipStream_t stream)
{
    const float* in_feat = (const float*)d_in[0];
    const int*   src     = (const int*)d_in[1];
    const int*   dst     = (const int*)d_in[2];
    const float* pw1 = (const float*)d_in[3];  const float* pb1 = (const float*)d_in[4];
    const float* sw1 = (const float*)d_in[5];  const float* sb1 = (const float*)d_in[6];
    const float* nw1 = (const float*)d_in[7];  const float* nb1 = (const float*)d_in[8];
    const float* pw2 = (const float*)d_in[9];  const float* pb2 = (const float*)d_in[10];
    const float* sw2 = (const float*)d_in[11]; const float* sb2 = (const float*)d_in[12];
    const float* nw2 = (const float*)d_in[13]; const float* nb2 = (const float*)d_in[14];
    float* out = (float*)d_out;

    const int M = in_sizes[0] / N_FEAT;   // 100000 nodes
    const int E = in_sizes[1];            // 1600000 edges
    const int NB = (M + (1 << BSHIFT) - 1) >> BSHIFT;   // 98 buckets

    // ---- workspace layout (256B-aligned regions) ----
    char* base = (char*)d_ws;
    size_t off = 0;
    auto alloc = [&](size_t bytes) { char* p = base + off; off = (off + bytes + 255) & ~(size_t)255; return p; };
    unsigned short* wb_p1 = (unsigned short*)alloc(16384 * 2);
    unsigned short* wb_s1 = (unsigned short*)alloc(16384 * 2);
    unsigned short* wb_n1 = (unsigned short*)alloc(16384 * 2);
    unsigned short* wb_p2 = (unsigned short*)alloc(16384 * 2);
    unsigned short* wb_s2 = (unsigned short*)alloc(6144 * 2);
    unsigned short* wb_n2 = (unsigned short*)alloc(6144 * 2);
    float* b_sn1 = (float*)alloc(128 * 4);
    float* b_sn2 = (float*)alloc(64 * 4);
    unsigned short* mb   = (unsigned short*)alloc((size_t)M * 128 * 2);
    unsigned short* agg  = (unsigned short*)alloc((size_t)M * 128 * 2);
    int* counts  = (int*)alloc((size_t)M * 4);
    int* offsets = (int*)alloc((size_t)M * 4);
    int* wgcnt   = (int*)alloc((size_t)NB * NWG_A * 4);
    int* binoff  = (int*)alloc(((size_t)NB * NWG_A + 1) * 4);
    unsigned* binned = (unsigned*)alloc((size_t)E * 4);
    int* csr     = (int*)alloc((size_t)E * 4);

    const int gemm_grid = (M + 127) / 128;              // 782
    const int gather_grid = (M * 64 + 255) / 256;       // one wave per node

    // prep + bin_count merged
    prep_bin_kernel<<<NWG_A + 64, 256, 0, stream>>>(
        pw1, sw1, nw1, pw2, sw2, nw2, sb1, nb1, sb2, nb2,
        wb_p1, wb_s1, wb_n1, wb_p2, wb_s2, wb_n2, b_sn1, b_sn2,
        dst, wgcnt, E, NB);
    bin_scan_kernel<<<1, 1024, 0, stream>>>(wgcnt, binoff, NB);
    // bin_scatter + pool1 GEMM merged
    scatter_pool_kernel<<<NWG_A + gemm_grid, 256, 0, stream>>>(
        src, dst, binoff, binned, E, NB,
        in_feat, wb_p1, pb1, mb, M);
    csr_build_kernel<<<NB, 1024, 0, stream>>>(binned, binoff, csr, offsets, counts, M);

    // ---- Layer 1 ----
    gather_max_kernel<<<gather_grid, 256, 0, stream>>>(
        (const u16x8*)mb, csr, offsets, counts, (u16x8*)agg, M);
    sn_pool_kernel<<<gemm_grid, 256, 0, stream>>>(
        in_feat, wb_s1, agg, wb_n1, b_sn1, wb_p2, pb2,
        wb_s2, b_sn2, mb, out, M);

    // ---- Layer 2 ----
    gather_max_kernel<<<gather_grid, 256, 0, stream>>>(
        (const u16x8*)mb, csr, offsets, counts, (u16x8*)agg, M);
    out_acc_kernel<<<gemm_grid, 256, 0, stream>>>(agg, wb_n2, out, M);
}